// Round 1
// baseline (87.577 us; speedup 1.0000x reference)
//
#include <hip/hip_runtime.h>
#include <math.h>

#define TPB 256
#define NODES 16
#define FEAT 19

__device__ __forceinline__ float softplus_f(float x) {
    // log(1+exp(x)) = max(x,0) + log1p(exp(-|x|)), fast-path transcendentals
    float e = __expf(-fabsf(x));
    return fmaxf(x, 0.0f) + __logf(1.0f + e);
}

__global__ __launch_bounds__(TPB) void mlp_fused_kernel(
    const float* __restrict__ Fs,
    const float* __restrict__ W1, const float* __restrict__ b1,
    const float* __restrict__ W2, const float* __restrict__ b2,
    const float* __restrict__ W3, const float* __restrict__ b3,
    const float* __restrict__ W4, const float* __restrict__ b4,
    float* __restrict__ out, int n)
{
    __shared__ float sF[TPB * 9];
    const int tid = threadIdx.x;
    const long long base = (long long)blockIdx.x * TPB;
    const int remain = n - (int)base;  // samples this block handles (may be < TPB at tail)
    const float* src = Fs + base * 9;

    if (remain >= TPB) {
        // full block: 2304 floats = 576 float4, coalesced
        const float4* s4 = (const float4*)src;
        float4* d4 = (float4*)sF;
        #pragma unroll
        for (int i = 0; i < (TPB * 9) / 4; i += TPB) {
            int idx = i + tid;
            if (idx < (TPB * 9) / 4) d4[idx] = s4[idx];
        }
    } else if (remain > 0) {
        int cnt = remain * 9;
        for (int i = tid; i < cnt; i += TPB) sF[i] = src[i];
    }
    __syncthreads();

    if (tid < remain) {
        const float* f = &sF[tid * 9];
        float a = f[0], b = f[1], c = f[2];
        float d = f[3], e = f[4], ff = f[5];
        float g = f[6], h = f[7], ii = f[8];

        // cofactor matrix C (== swapaxes(inv(F),1,2) * det)
        float C00 = e * ii - ff * h;
        float C01 = ff * g - d * ii;
        float C02 = d * h - e * g;
        float C10 = c * h - b * ii;
        float C11 = a * ii - c * g;
        float C12 = b * g - a * h;
        float C20 = b * ff - c * e;
        float C21 = c * d - a * ff;
        float C22 = a * e - b * d;
        float det = a * C00 + b * C01 + c * C02;

        float x[FEAT];
        x[0] = a;  x[1] = b;  x[2] = c;
        x[3] = d;  x[4] = e;  x[5] = ff;
        x[6] = g;  x[7] = h;  x[8] = ii;
        x[9]  = C00; x[10] = C01; x[11] = C02;
        x[12] = C10; x[13] = C11; x[14] = C12;
        x[15] = C20; x[16] = C21; x[17] = C22;
        x[18] = det;

        // Layer 1: 19 -> 16, softplus. Weight reads are wave-uniform -> s_load.
        float h1[NODES];
        #pragma unroll
        for (int j = 0; j < NODES; ++j) h1[j] = b1[j];
        #pragma unroll
        for (int k = 0; k < FEAT; ++k) {
            float xv = x[k];
            #pragma unroll
            for (int j = 0; j < NODES; ++j) h1[j] = fmaf(xv, W1[k * NODES + j], h1[j]);
        }
        #pragma unroll
        for (int j = 0; j < NODES; ++j) h1[j] = softplus_f(h1[j]);

        // Layer 2: 16 -> 16, softplus
        float h2[NODES];
        #pragma unroll
        for (int j = 0; j < NODES; ++j) h2[j] = b2[j];
        #pragma unroll
        for (int k = 0; k < NODES; ++k) {
            float xv = h1[k];
            #pragma unroll
            for (int j = 0; j < NODES; ++j) h2[j] = fmaf(xv, W2[k * NODES + j], h2[j]);
        }
        #pragma unroll
        for (int j = 0; j < NODES; ++j) h2[j] = softplus_f(h2[j]);

        // Layer 3: 16 -> 16, softplus
        float h3[NODES];
        #pragma unroll
        for (int j = 0; j < NODES; ++j) h3[j] = b3[j];
        #pragma unroll
        for (int k = 0; k < NODES; ++k) {
            float xv = h2[k];
            #pragma unroll
            for (int j = 0; j < NODES; ++j) h3[j] = fmaf(xv, W3[k * NODES + j], h3[j]);
        }
        #pragma unroll
        for (int j = 0; j < NODES; ++j) h3[j] = softplus_f(h3[j]);

        // Layer 4: 16 -> 1, linear
        float y = b4[0];
        #pragma unroll
        for (int k = 0; k < NODES; ++k) y = fmaf(h3[k], W4[k], y);

        out[base + tid] = y;
    }
}

extern "C" void kernel_launch(void* const* d_in, const int* in_sizes, int n_in,
                              void* d_out, int out_size, void* d_ws, size_t ws_size,
                              hipStream_t stream) {
    const float* Fs = (const float*)d_in[0];
    const float* W1 = (const float*)d_in[1];
    const float* b1 = (const float*)d_in[2];
    const float* W2 = (const float*)d_in[3];
    const float* b2 = (const float*)d_in[4];
    const float* W3 = (const float*)d_in[5];
    const float* b3 = (const float*)d_in[6];
    const float* W4 = (const float*)d_in[7];
    const float* b4 = (const float*)d_in[8];
    float* out = (float*)d_out;

    int n = in_sizes[0] / 9;  // N samples
    int grid = (n + TPB - 1) / TPB;
    mlp_fused_kernel<<<grid, TPB, 0, stream>>>(Fs, W1, b1, W2, b2, W3, b3, W4, b4, out, n);
}

// Round 2
// 82.709 us; speedup vs baseline: 1.0589x; 1.0589x over previous
//
#include <hip/hip_runtime.h>
#include <math.h>

#define TPB 256
#define NODES 16
#define FEAT 19

typedef float f2 __attribute__((ext_vector_type(2)));

__device__ __forceinline__ float softplus_f(float x) {
    // softplus(x) = max(x,0) + log1p(exp(-|x|))
    float m = fminf(x, -x);           // -|x|  (v_min_f32 with neg modifier)
    float e = __expf(m);              // exp(-|x|) <= 1, no overflow
    return fmaxf(x, 0.0f) + __logf(1.0f + e);
}

__global__ __launch_bounds__(TPB) void mlp_fused_kernel(
    const float* __restrict__ Fs,
    const float* __restrict__ W1, const float* __restrict__ b1,
    const float* __restrict__ W2, const float* __restrict__ b2,
    const float* __restrict__ W3, const float* __restrict__ b3,
    const float* __restrict__ W4, const float* __restrict__ b4,
    float* __restrict__ out, int n)
{
    __shared__ float sF[TPB * 9];
    const int tid = threadIdx.x;
    const long long base = (long long)blockIdx.x * TPB;
    const int remain = n - (int)base;
    const float* src = Fs + base * 9;

    if (remain >= TPB) {
        const float4* s4 = (const float4*)src;
        float4* d4 = (float4*)sF;
        #pragma unroll
        for (int i = 0; i < (TPB * 9) / 4; i += TPB) {
            int idx = i + tid;
            if (idx < (TPB * 9) / 4) d4[idx] = s4[idx];
        }
    } else if (remain > 0) {
        int cnt = remain * 9;
        for (int i = tid; i < cnt; i += TPB) sF[i] = src[i];
    }
    __syncthreads();

    if (tid < remain) {
        const float* f = &sF[tid * 9];
        float a = f[0], b = f[1], c = f[2];
        float d = f[3], e = f[4], ff = f[5];
        float g = f[6], h = f[7], ii = f[8];

        // ---------- Layer 1 (19 -> 16) with packed fp32 FMA ----------
        f2 acc[NODES / 2];
        const f2* b1p = (const f2*)b1;
        #pragma unroll
        for (int j = 0; j < NODES / 2; ++j) acc[j] = b1p[j];

        // FMA one feature against its weight row (8 packed FMAs)
        #define FMA_ROW(xv, row_idx, W)                                          \
            do {                                                                 \
                f2 xs = {(xv), (xv)};                                            \
                const f2* wr = (const f2*)((W) + (row_idx) * NODES);             \
                _Pragma("unroll")                                                \
                for (int j = 0; j < NODES / 2; ++j)                              \
                    acc[j] = __builtin_elementwise_fma(xs, wr[j], acc[j]);       \
            } while (0)

        FMA_ROW(a, 0, W1); FMA_ROW(b, 1, W1); FMA_ROW(c, 2, W1);
        FMA_ROW(d, 3, W1); FMA_ROW(e, 4, W1); FMA_ROW(ff, 5, W1);
        FMA_ROW(g, 6, W1); FMA_ROW(h, 7, W1); FMA_ROW(ii, 8, W1);

        // cofactors (consume immediately; det from first row of cofactors)
        float C00 = e * ii - ff * h;
        float C01 = ff * g - d * ii;
        float C02 = d * h - e * g;
        float det = fmaf(a, C00, fmaf(b, C01, c * C02));
        FMA_ROW(C00, 9, W1); FMA_ROW(C01, 10, W1); FMA_ROW(C02, 11, W1);
        float C10 = c * h - b * ii;
        float C11 = a * ii - c * g;
        float C12 = b * g - a * h;
        FMA_ROW(C10, 12, W1); FMA_ROW(C11, 13, W1); FMA_ROW(C12, 14, W1);
        float C20 = b * ff - c * e;
        float C21 = c * d - a * ff;
        float C22 = a * e - b * d;
        FMA_ROW(C20, 15, W1); FMA_ROW(C21, 16, W1); FMA_ROW(C22, 17, W1);
        FMA_ROW(det, 18, W1);

        float hv[NODES];
        #pragma unroll
        for (int j = 0; j < NODES / 2; ++j) {
            hv[2 * j]     = softplus_f(acc[j].x);
            hv[2 * j + 1] = softplus_f(acc[j].y);
        }

        // ---------- Layer 2 (16 -> 16) ----------
        const f2* b2p = (const f2*)b2;
        #pragma unroll
        for (int j = 0; j < NODES / 2; ++j) acc[j] = b2p[j];
        #pragma unroll
        for (int k = 0; k < NODES; ++k) FMA_ROW(hv[k], k, W2);
        #pragma unroll
        for (int j = 0; j < NODES / 2; ++j) {
            hv[2 * j]     = softplus_f(acc[j].x);
            hv[2 * j + 1] = softplus_f(acc[j].y);
        }

        // ---------- Layer 3 (16 -> 16) ----------
        const f2* b3p = (const f2*)b3;
        #pragma unroll
        for (int j = 0; j < NODES / 2; ++j) acc[j] = b3p[j];
        #pragma unroll
        for (int k = 0; k < NODES; ++k) FMA_ROW(hv[k], k, W3);
        #pragma unroll
        for (int j = 0; j < NODES / 2; ++j) {
            hv[2 * j]     = softplus_f(acc[j].x);
            hv[2 * j + 1] = softplus_f(acc[j].y);
        }

        // ---------- Layer 4 (16 -> 1) ----------
        float y = b4[0];
        #pragma unroll
        for (int k = 0; k < NODES; ++k) y = fmaf(hv[k], W4[k], y);

        out[base + tid] = y;
        #undef FMA_ROW
    }
}

extern "C" void kernel_launch(void* const* d_in, const int* in_sizes, int n_in,
                              void* d_out, int out_size, void* d_ws, size_t ws_size,
                              hipStream_t stream) {
    const float* Fs = (const float*)d_in[0];
    const float* W1 = (const float*)d_in[1];
    const float* b1 = (const float*)d_in[2];
    const float* W2 = (const float*)d_in[3];
    const float* b2 = (const float*)d_in[4];
    const float* W3 = (const float*)d_in[5];
    const float* b3 = (const float*)d_in[6];
    const float* W4 = (const float*)d_in[7];
    const float* b4 = (const float*)d_in[8];
    float* out = (float*)d_out;

    int n = in_sizes[0] / 9;
    int grid = (n + TPB - 1) / TPB;
    mlp_fused_kernel<<<grid, TPB, 0, stream>>>(Fs, W1, b1, W2, b2, W3, b3, W4, b4, out, n);
}

// Round 6
// 46.420 us; speedup vs baseline: 1.8866x; 1.7818x over previous
//
#include <hip/hip_runtime.h>
#include <math.h>

#define TPB 256
#define NODES 16
#define FEAT 19
#define BLOCKS 1024

typedef float f2 __attribute__((ext_vector_type(2)));
typedef float f32x4 __attribute__((ext_vector_type(4)));
typedef _Float16 half4 __attribute__((ext_vector_type(4)));

#define LOG2E 1.44269504088896340736f
#define LN2   0.69314718055994530942f

__device__ __forceinline__ float sp_any(float t) {
    // softplus(x)/ln2 where t = x*log2e: max(t,0) + log2(1+2^-|t|)
    float nt = fminf(t, -t);
    float e  = __builtin_amdgcn_exp2f(nt);
    float lg = __builtin_amdgcn_logf(1.0f + e);   // native log2
    return fmaxf(t, 0.0f) + lg;
}
__device__ __forceinline__ float sp_pos(float t) {
    // t >= 0 guaranteed here: W2,W3 >= 0 (jnp.abs), h >= 0 (softplus), b2,b3 = 0
    float e  = __builtin_amdgcn_exp2f(-t);
    float lg = __builtin_amdgcn_logf(1.0f + e);
    return t + lg;
}

// pack two f32 -> one dword of 2x f16 (rtz), type-erased
__device__ __forceinline__ unsigned int pk2(float a, float b) {
    return __builtin_bit_cast(unsigned int, __builtin_amdgcn_cvt_pkrtz(a, b));
}

__global__ __launch_bounds__(TPB, 4) void mlp_mfma_kernel(
    const float* __restrict__ Fs,
    const float* __restrict__ W1, const float* __restrict__ b1,
    const float* __restrict__ W2, const float* __restrict__ b2,
    const float* __restrict__ W3, const float* __restrict__ b3,
    const float* __restrict__ W4, const float* __restrict__ b4,
    float* __restrict__ out, int n, int iters)
{
    __shared__ unsigned int lds[4][640];           // per-wave: 64 samples x 5 uint2 slots
    const int tid = threadIdx.x;
    const int l = tid & 63, w = tid >> 6;
    const int g = l >> 4, c = l & 15;

    // ---- one-time per-lane fragments/biases (amortized over iters) ----
    // A-frag for 16x16x16f16: lane holds A[row=c][k=4g+j]; we need A[m][k]=W[k][m]
    half4 a2, a3;
    f32x4 cb2, cb3;
    float w4v[4];
    #pragma unroll
    for (int j = 0; j < 4; ++j) {
        a2[j] = (_Float16)W2[(4*g+j)*NODES + c];
        a3[j] = (_Float16)W3[(4*g+j)*NODES + c];
    }
    #pragma unroll
    for (int i = 0; i < 4; ++i) {
        cb2[i] = b2[4*g+i] * LOG2E;
        cb3[i] = b3[4*g+i] * LOG2E;
        w4v[i] = W4[4*g+i] * LN2;
    }
    const float b4s = b4[0];

    unsigned int* ldsw = &lds[w][0];
    const long long s0 = ((long long)blockIdx.x * 4 + w) * (64LL * iters);

    for (int it = 0; it < iters; ++it) {
        long long ws = s0 + (long long)it * 64;
        if (ws >= n) break;

        // ---- load F for this lane's sample (clamped at tail) ----
        long long sE = ws + l; if (sE > n - 1) sE = n - 1;
        const float* fp = Fs + sE * 9;
        float a = fp[0], b = fp[1], cc = fp[2];
        float d = fp[3], e = fp[4], f5 = fp[5];
        float g7 = fp[6], h7 = fp[7], i8 = fp[8];

        // ---- Layer 1 (19->16) on VALU, packed fp32 FMA ----
        f2 acc[NODES/2];
        const f2* b1p = (const f2*)b1;
        #pragma unroll
        for (int j = 0; j < NODES/2; ++j) acc[j] = b1p[j];

        #define FMA_ROW(xv, row_idx)                                             \
            do {                                                                 \
                f2 xs = {(xv), (xv)};                                            \
                const f2* wr = (const f2*)(W1 + (row_idx) * NODES);              \
                _Pragma("unroll")                                                \
                for (int j = 0; j < NODES/2; ++j)                                \
                    acc[j] = __builtin_elementwise_fma(xs, wr[j], acc[j]);       \
            } while (0)

        FMA_ROW(a, 0); FMA_ROW(b, 1); FMA_ROW(cc, 2);
        FMA_ROW(d, 3); FMA_ROW(e, 4); FMA_ROW(f5, 5);
        FMA_ROW(g7, 6); FMA_ROW(h7, 7); FMA_ROW(i8, 8);

        float C00 = e * i8 - f5 * h7;
        float C01 = f5 * g7 - d * i8;
        float C02 = d * h7 - e * g7;
        float det = fmaf(a, C00, fmaf(b, C01, cc * C02));
        FMA_ROW(C00, 9); FMA_ROW(C01, 10); FMA_ROW(C02, 11);
        float C10 = cc * h7 - b * i8;
        float C11 = a * i8 - cc * g7;
        float C12 = b * g7 - a * h7;
        FMA_ROW(C10, 12); FMA_ROW(C11, 13); FMA_ROW(C12, 14);
        float C20 = b * f5 - cc * e;
        float C21 = cc * d - a * f5;
        float C22 = a * e - b * d;
        FMA_ROW(C20, 15); FMA_ROW(C21, 16); FMA_ROW(C22, 17);
        FMA_ROW(det, 18);
        #undef FMA_ROW

        // log2-domain softplus; store h1/ln2 as packed f16 dwords
        unsigned int pk[8];
        #pragma unroll
        for (int j = 0; j < NODES/2; ++j) {
            float t0 = acc[j].x * LOG2E;
            float t1 = acc[j].y * LOG2E;
            pk[j] = pk2(sp_any(t0), sp_any(t1));
        }

        // ---- transpose h1 (64 samples x 16 halves) via per-wave LDS ----
        // sample s stores uint2 chunk cidx (nodes 8*cidx..) at slot s*5 + ((cidx+s>>4)&3)
        {
            uint2* basep = (uint2*)ldsw;
            #pragma unroll
            for (int cidx = 0; cidx < 4; ++cidx) {
                uint2 v; v.x = pk[2*cidx]; v.y = pk[2*cidx+1];
                basep[l*5 + ((cidx + g) & 3)] = v;
            }
        }
        asm volatile("s_waitcnt lgkmcnt(0)" ::: "memory");

        half4 bf[4];
        {
            const uint2* basep = (const uint2*)ldsw;
            #pragma unroll
            for (int m = 0; m < 4; ++m) {
                int sm = 16*m + c;                      // source sample in wave
                uint2 r = basep[sm*5 + ((g + m) & 3)];  // chunk g of sample sm
                bf[m] = __builtin_bit_cast(half4, r);
            }
        }

        // ---- Layer 2: 4x mfma 16x16x16 f16 (C-init = b2*log2e) ----
        f32x4 d20 = __builtin_amdgcn_mfma_f32_16x16x16f16(a2, bf[0], cb2, 0, 0, 0);
        f32x4 d21 = __builtin_amdgcn_mfma_f32_16x16x16f16(a2, bf[1], cb2, 0, 0, 0);
        f32x4 d22 = __builtin_amdgcn_mfma_f32_16x16x16f16(a2, bf[2], cb2, 0, 0, 0);
        f32x4 d23 = __builtin_amdgcn_mfma_f32_16x16x16f16(a2, bf[3], cb2, 0, 0, 0);

        // softplus (t>=0) + pack to f16: D-layout == next B-layout, no shuffle
        half4 nb0, nb1, nb2, nb3;
        {
            uint2 u;
            u.x = pk2(sp_pos(d20[0]), sp_pos(d20[1]));
            u.y = pk2(sp_pos(d20[2]), sp_pos(d20[3]));
            nb0 = __builtin_bit_cast(half4, u);
            u.x = pk2(sp_pos(d21[0]), sp_pos(d21[1]));
            u.y = pk2(sp_pos(d21[2]), sp_pos(d21[3]));
            nb1 = __builtin_bit_cast(half4, u);
            u.x = pk2(sp_pos(d22[0]), sp_pos(d22[1]));
            u.y = pk2(sp_pos(d22[2]), sp_pos(d22[3]));
            nb2 = __builtin_bit_cast(half4, u);
            u.x = pk2(sp_pos(d23[0]), sp_pos(d23[1]));
            u.y = pk2(sp_pos(d23[2]), sp_pos(d23[3]));
            nb3 = __builtin_bit_cast(half4, u);
        }

        // ---- Layer 3 ----
        f32x4 d30 = __builtin_amdgcn_mfma_f32_16x16x16f16(a3, nb0, cb3, 0, 0, 0);
        f32x4 d31 = __builtin_amdgcn_mfma_f32_16x16x16f16(a3, nb1, cb3, 0, 0, 0);
        f32x4 d32 = __builtin_amdgcn_mfma_f32_16x16x16f16(a3, nb2, cb3, 0, 0, 0);
        f32x4 d33 = __builtin_amdgcn_mfma_f32_16x16x16f16(a3, nb3, cb3, 0, 0, 0);

        // ---- Layer 4: softplus then dot with W4*ln2; reduce over g-groups ----
        float y0 = sp_pos(d30[0])*w4v[0] + sp_pos(d30[1])*w4v[1] + sp_pos(d30[2])*w4v[2] + sp_pos(d30[3])*w4v[3];
        float y1 = sp_pos(d31[0])*w4v[0] + sp_pos(d31[1])*w4v[1] + sp_pos(d31[2])*w4v[2] + sp_pos(d31[3])*w4v[3];
        float y2 = sp_pos(d32[0])*w4v[0] + sp_pos(d32[1])*w4v[1] + sp_pos(d32[2])*w4v[2] + sp_pos(d32[3])*w4v[3];
        float y3 = sp_pos(d33[0])*w4v[0] + sp_pos(d33[1])*w4v[1] + sp_pos(d33[2])*w4v[2] + sp_pos(d33[3])*w4v[3];

        y0 += __shfl_xor(y0, 16, 64); y0 += __shfl_xor(y0, 32, 64);
        y1 += __shfl_xor(y1, 16, 64); y1 += __shfl_xor(y1, 32, 64);
        y2 += __shfl_xor(y2, 16, 64); y2 += __shfl_xor(y2, 32, 64);
        y3 += __shfl_xor(y3, 16, 64); y3 += __shfl_xor(y3, 32, 64);

        float yo = (g == 0) ? y0 : ((g == 1) ? y1 : ((g == 2) ? y2 : y3));
        yo += b4s;

        if (ws + l < n) out[ws + l] = yo;
    }
}

extern "C" void kernel_launch(void* const* d_in, const int* in_sizes, int n_in,
                              void* d_out, int out_size, void* d_ws, size_t ws_size,
                              hipStream_t stream) {
    const float* Fs = (const float*)d_in[0];
    const float* W1 = (const float*)d_in[1];
    const float* b1 = (const float*)d_in[2];
    const float* W2 = (const float*)d_in[3];
    const float* b2 = (const float*)d_in[4];
    const float* W3 = (const float*)d_in[5];
    const float* b3 = (const float*)d_in[6];
    const float* W4 = (const float*)d_in[7];
    const float* b4 = (const float*)d_in[8];
    float* out = (float*)d_out;

    int n = in_sizes[0] / 9;
    int waves = (n + 63) / 64;
    int iters = (waves + BLOCKS * 4 - 1) / (BLOCKS * 4);
    mlp_mfma_kernel<<<BLOCKS, TPB, 0, stream>>>(Fs, W1, b1, W2, b2, W3, b3, W4, b4,
                                                out, n, iters);
}

// Round 7
// 43.851 us; speedup vs baseline: 1.9972x; 1.0586x over previous
//
#include <hip/hip_runtime.h>
#include <math.h>

#define TPB 256
#define NODES 16
#define FEAT 19
#define BLOCKS 2048

typedef float f2 __attribute__((ext_vector_type(2)));
typedef float f32x4 __attribute__((ext_vector_type(4)));
typedef _Float16 half4 __attribute__((ext_vector_type(4)));

#define LOG2E 1.44269504088896340736f
#define LN2   0.69314718055994530942f

__device__ __forceinline__ float sp_any(float t) {
    // softplus(x)/ln2 where t = x*log2e: max(t,0) + log2(1+2^-|t|)
    float nt = fminf(t, -t);
    float e  = __builtin_amdgcn_exp2f(nt);
    float lg = __builtin_amdgcn_logf(1.0f + e);   // native log2
    return fmaxf(t, 0.0f) + lg;
}
__device__ __forceinline__ float sp_pos(float t) {
    // t >= 0 guaranteed here: W2,W3 >= 0 (jnp.abs), h >= 0 (softplus), b2,b3 = 0
    float e  = __builtin_amdgcn_exp2f(-t);
    float lg = __builtin_amdgcn_logf(1.0f + e);
    return t + lg;
}

// pack two f32 -> one dword of 2x f16 (rtz), type-erased
__device__ __forceinline__ unsigned int pk2(float a, float b) {
    return __builtin_bit_cast(unsigned int, __builtin_amdgcn_cvt_pkrtz(a, b));
}

__global__ __launch_bounds__(TPB, 4) void mlp_mfma_kernel(
    const float* __restrict__ Fs,
    const float* __restrict__ W1, const float* __restrict__ b1,
    const float* __restrict__ W2, const float* __restrict__ b2,
    const float* __restrict__ W3, const float* __restrict__ b3,
    const float* __restrict__ W4, const float* __restrict__ b4,
    float* __restrict__ out, int n, int iters)
{
    __shared__ unsigned int lds[4][640];           // per-wave: 64 samples x 5 uint2 slots
    const int tid = threadIdx.x;
    const int l = tid & 63, w = tid >> 6;
    const int g = l >> 4, c = l & 15;

    // ---- one-time per-lane fragments/biases (amortized over iters) ----
    // A-frag for 16x16x16f16: lane holds A[row=c][k=4g+j]; we need A[m][k]=W[k][m]
    half4 a2, a3;
    f32x4 cb2, cb3;
    float w4v[4];
    #pragma unroll
    for (int j = 0; j < 4; ++j) {
        a2[j] = (_Float16)W2[(4*g+j)*NODES + c];
        a3[j] = (_Float16)W3[(4*g+j)*NODES + c];
    }
    #pragma unroll
    for (int i = 0; i < 4; ++i) {
        cb2[i] = b2[4*g+i] * LOG2E;
        cb3[i] = b3[4*g+i] * LOG2E;
        w4v[i] = W4[4*g+i] * LN2;
    }
    const float b4s = b4[0];

    unsigned int* ldsw = &lds[w][0];
    const long long s0 = ((long long)blockIdx.x * 4 + w) * (64LL * iters);
    if (s0 >= n) return;

    // ---- prologue: load F for iteration 0 (clamped) ----
    float fr[9];
    {
        long long sE = s0 + l; if (sE > n - 1) sE = n - 1;
        const float* fp = Fs + sE * 9;
        #pragma unroll
        for (int q = 0; q < 9; ++q) fr[q] = fp[q];
    }

    for (int it = 0; it < iters; ++it) {
        long long ws = s0 + (long long)it * 64;
        if (ws >= n) break;

        // ---- prefetch next iteration's F early (hides HBM latency) ----
        float nf[9];
        const bool havenext = (it + 1 < iters) && (ws + 64 < n);
        if (havenext) {
            long long sE = ws + 64 + l; if (sE > n - 1) sE = n - 1;
            const float* fp = Fs + sE * 9;
            #pragma unroll
            for (int q = 0; q < 9; ++q) nf[q] = fp[q];
        }

        float a = fr[0], b = fr[1], cc = fr[2];
        float d = fr[3], e = fr[4], f5 = fr[5];
        float g7 = fr[6], h7 = fr[7], i8 = fr[8];

        // ---- Layer 1 (19->16) on VALU, packed fp32 FMA ----
        f2 acc[NODES/2];
        const f2* b1p = (const f2*)b1;
        #pragma unroll
        for (int j = 0; j < NODES/2; ++j) acc[j] = b1p[j];

        #define FMA_ROW(xv, row_idx)                                             \
            do {                                                                 \
                f2 xs = {(xv), (xv)};                                            \
                const f2* wr = (const f2*)(W1 + (row_idx) * NODES);              \
                _Pragma("unroll")                                                \
                for (int j = 0; j < NODES/2; ++j)                                \
                    acc[j] = __builtin_elementwise_fma(xs, wr[j], acc[j]);       \
            } while (0)

        FMA_ROW(a, 0); FMA_ROW(b, 1); FMA_ROW(cc, 2);
        FMA_ROW(d, 3); FMA_ROW(e, 4); FMA_ROW(f5, 5);
        FMA_ROW(g7, 6); FMA_ROW(h7, 7); FMA_ROW(i8, 8);

        float C00 = e * i8 - f5 * h7;
        float C01 = f5 * g7 - d * i8;
        float C02 = d * h7 - e * g7;
        float det = fmaf(a, C00, fmaf(b, C01, cc * C02));
        FMA_ROW(C00, 9); FMA_ROW(C01, 10); FMA_ROW(C02, 11);
        float C10 = cc * h7 - b * i8;
        float C11 = a * i8 - cc * g7;
        float C12 = b * g7 - a * h7;
        FMA_ROW(C10, 12); FMA_ROW(C11, 13); FMA_ROW(C12, 14);
        float C20 = b * f5 - cc * e;
        float C21 = cc * d - a * f5;
        float C22 = a * e - b * d;
        FMA_ROW(C20, 15); FMA_ROW(C21, 16); FMA_ROW(C22, 17);
        FMA_ROW(det, 18);
        #undef FMA_ROW

        // log2-domain softplus; store h1/ln2 as packed f16 dwords
        unsigned int pk[8];
        #pragma unroll
        for (int j = 0; j < NODES/2; ++j) {
            float t0 = acc[j].x * LOG2E;
            float t1 = acc[j].y * LOG2E;
            pk[j] = pk2(sp_any(t0), sp_any(t1));
        }

        // ---- transpose h1 (64 samples x 16 halves) via per-wave LDS ----
        // sample s stores uint2 chunk cidx at slot s*5 + ((cidx + s>>4) & 3)
        {
            uint2* basep = (uint2*)ldsw;
            #pragma unroll
            for (int cidx = 0; cidx < 4; ++cidx) {
                uint2 v; v.x = pk[2*cidx]; v.y = pk[2*cidx+1];
                basep[l*5 + ((cidx + g) & 3)] = v;
            }
        }
        asm volatile("s_waitcnt lgkmcnt(0)" ::: "memory");

        half4 bf[4];
        {
            const uint2* basep = (const uint2*)ldsw;
            #pragma unroll
            for (int m = 0; m < 4; ++m) {
                int sm = 16*m + c;                      // source sample in wave
                uint2 r = basep[sm*5 + ((g + m) & 3)];  // chunk g of sample sm
                bf[m] = __builtin_bit_cast(half4, r);
            }
        }

        // ---- Layer 2: 4x mfma 16x16x16 f16 (C-init = b2*log2e) ----
        f32x4 d20 = __builtin_amdgcn_mfma_f32_16x16x16f16(a2, bf[0], cb2, 0, 0, 0);
        f32x4 d21 = __builtin_amdgcn_mfma_f32_16x16x16f16(a2, bf[1], cb2, 0, 0, 0);
        f32x4 d22 = __builtin_amdgcn_mfma_f32_16x16x16f16(a2, bf[2], cb2, 0, 0, 0);
        f32x4 d23 = __builtin_amdgcn_mfma_f32_16x16x16f16(a2, bf[3], cb2, 0, 0, 0);

        // softplus (t>=0) + pack to f16: D-layout == next B-layout, no shuffle
        half4 nb0, nb1, nb2, nb3;
        {
            uint2 u;
            u.x = pk2(sp_pos(d20[0]), sp_pos(d20[1]));
            u.y = pk2(sp_pos(d20[2]), sp_pos(d20[3]));
            nb0 = __builtin_bit_cast(half4, u);
            u.x = pk2(sp_pos(d21[0]), sp_pos(d21[1]));
            u.y = pk2(sp_pos(d21[2]), sp_pos(d21[3]));
            nb1 = __builtin_bit_cast(half4, u);
            u.x = pk2(sp_pos(d22[0]), sp_pos(d22[1]));
            u.y = pk2(sp_pos(d22[2]), sp_pos(d22[3]));
            nb2 = __builtin_bit_cast(half4, u);
            u.x = pk2(sp_pos(d23[0]), sp_pos(d23[1]));
            u.y = pk2(sp_pos(d23[2]), sp_pos(d23[3]));
            nb3 = __builtin_bit_cast(half4, u);
        }

        // ---- Layer 3 ----
        f32x4 d30 = __builtin_amdgcn_mfma_f32_16x16x16f16(a3, nb0, cb3, 0, 0, 0);
        f32x4 d31 = __builtin_amdgcn_mfma_f32_16x16x16f16(a3, nb1, cb3, 0, 0, 0);
        f32x4 d32 = __builtin_amdgcn_mfma_f32_16x16x16f16(a3, nb2, cb3, 0, 0, 0);
        f32x4 d33 = __builtin_amdgcn_mfma_f32_16x16x16f16(a3, nb3, cb3, 0, 0, 0);

        // ---- Layer 4: softplus then dot with W4*ln2; reduce over g-groups ----
        float y0 = sp_pos(d30[0])*w4v[0] + sp_pos(d30[1])*w4v[1] + sp_pos(d30[2])*w4v[2] + sp_pos(d30[3])*w4v[3];
        float y1 = sp_pos(d31[0])*w4v[0] + sp_pos(d31[1])*w4v[1] + sp_pos(d31[2])*w4v[2] + sp_pos(d31[3])*w4v[3];
        float y2 = sp_pos(d32[0])*w4v[0] + sp_pos(d32[1])*w4v[1] + sp_pos(d32[2])*w4v[2] + sp_pos(d32[3])*w4v[3];
        float y3 = sp_pos(d33[0])*w4v[0] + sp_pos(d33[1])*w4v[1] + sp_pos(d33[2])*w4v[2] + sp_pos(d33[3])*w4v[3];

        y0 += __shfl_xor(y0, 16, 64); y0 += __shfl_xor(y0, 32, 64);
        y1 += __shfl_xor(y1, 16, 64); y1 += __shfl_xor(y1, 32, 64);
        y2 += __shfl_xor(y2, 16, 64); y2 += __shfl_xor(y2, 32, 64);
        y3 += __shfl_xor(y3, 16, 64); y3 += __shfl_xor(y3, 32, 64);

        float yo = (g == 0) ? y0 : ((g == 1) ? y1 : ((g == 2) ? y2 : y3));
        yo += b4s;

        if (ws + l < n) out[ws + l] = yo;

        // rotate prefetched F into place
        if (havenext) {
            #pragma unroll
            for (int q = 0; q < 9; ++q) fr[q] = nf[q];
        }
    }
}

extern "C" void kernel_launch(void* const* d_in, const int* in_sizes, int n_in,
                              void* d_out, int out_size, void* d_ws, size_t ws_size,
                              hipStream_t stream) {
    const float* Fs = (const float*)d_in[0];
    const float* W1 = (const float*)d_in[1];
    const float* b1 = (const float*)d_in[2];
    const float* W2 = (const float*)d_in[3];
    const float* b2 = (const float*)d_in[4];
    const float* W3 = (const float*)d_in[5];
    const float* b3 = (const float*)d_in[6];
    const float* W4 = (const float*)d_in[7];
    const float* b4 = (const float*)d_in[8];
    float* out = (float*)d_out;

    int n = in_sizes[0] / 9;
    int waves = (n + 63) / 64;
    int iters = (waves + BLOCKS * 4 - 1) / (BLOCKS * 4);
    mlp_mfma_kernel<<<BLOCKS, TPB, 0, stream>>>(Fs, W1, b1, W2, b2, W3, b3, W4, b4,
                                                out, n, iters);
}

// Round 8
// 34.608 us; speedup vs baseline: 2.5305x; 1.2671x over previous
//
#include <hip/hip_runtime.h>
#include <math.h>

#define TPB 256
#define NODES 16
#define BLOCKS 2048

typedef float f32x4 __attribute__((ext_vector_type(4)));
typedef _Float16 half4 __attribute__((ext_vector_type(4)));

#define LOG2E 1.44269504088896340736f
#define LN2   0.69314718055994530942f

__device__ __forceinline__ float sp_any(float t) {
    // softplus(x)/ln2 with t = x*log2e: max(t,0) + log2(1+2^-|t|)
    float nt = fminf(t, -t);
    float e  = __builtin_amdgcn_exp2f(nt);
    float lg = __builtin_amdgcn_logf(1.0f + e);   // native log2
    return fmaxf(t, 0.0f) + lg;
}
__device__ __forceinline__ float sp_pos(float t) {
    // t >= 0 guaranteed: W2,W3 >= 0 (jnp.abs), h >= 0, b2,b3 = 0
    float e  = __builtin_amdgcn_exp2f(-t);
    float lg = __builtin_amdgcn_logf(1.0f + e);
    return t + lg;
}
// pack two f32 -> one dword of 2x f16 (rtz), type-erased
__device__ __forceinline__ unsigned int pk2(float a, float b) {
    return __builtin_bit_cast(unsigned int, __builtin_amdgcn_cvt_pkrtz(a, b));
}
__device__ __forceinline__ half4 h4(uint2 u) {
    return __builtin_bit_cast(half4, u);
}

__global__ __launch_bounds__(TPB, 4) void mlp_mfma_kernel(
    const float* __restrict__ Fs,
    const float* __restrict__ W1, const float* __restrict__ b1,
    const float* __restrict__ W2, const float* __restrict__ b2,
    const float* __restrict__ W3, const float* __restrict__ b3,
    const float* __restrict__ W4, const float* __restrict__ b4,
    float* __restrict__ out, int n, int iters)
{
    __shared__ uint2 lds[4][320];        // per-wave: 64 samples x 5 uint2 (19 f16 feats + pad)
    const int tid = threadIdx.x;
    const int l = tid & 63, w = tid >> 6;
    const int g = l >> 4, c = l & 15;

    // ---- one-time per-lane fragments/biases; NO weight loads inside the loop ----
    // A-frag (16x16x16f16): lane holds A[row=c][k=4g+j]; A[m][k] = W[k][m] (transposed gather).
    // Layer 1 runs K=32 as two chained K=16 MFMAs; W1 rows 19..31 are zero.
    // log2e is folded into W1 and b1 so L1 output is already t-domain.
    half4 a1lo, a1hi, a2, a3;
    f32x4 cb1, cb2, cb3;
    float w4v[4];
    #pragma unroll
    for (int j = 0; j < 4; ++j) {
        a1lo[j] = (_Float16)(W1[(4*g+j)*NODES + c] * LOG2E);
        a1hi[j] = (_Float16)((g == 0 && j < 3) ? W1[(16+j)*NODES + c] * LOG2E : 0.0f);
        a2[j]   = (_Float16)W2[(4*g+j)*NODES + c];
        a3[j]   = (_Float16)W3[(4*g+j)*NODES + c];
    }
    #pragma unroll
    for (int i = 0; i < 4; ++i) {
        cb1[i] = b1[4*g+i] * LOG2E;
        cb2[i] = b2[4*g+i] * LOG2E;
        cb3[i] = b3[4*g+i] * LOG2E;
        w4v[i] = W4[4*g+i] * LN2;
    }
    const float b4s = b4[0];

    uint2* basep = &lds[w][0];
    const long long s0 = ((long long)blockIdx.x * 4 + w) * (64LL * iters);
    if (s0 >= n) return;

    // ---- prologue: load F for iteration 0 (clamped) ----
    float fr[9];
    {
        long long sE = s0 + l; if (sE > n - 1) sE = n - 1;
        const float* fp = Fs + sE * 9;
        #pragma unroll
        for (int q = 0; q < 9; ++q) fr[q] = fp[q];
    }

    for (int it = 0; it < iters; ++it) {
        long long ws = s0 + (long long)it * 64;
        if (ws >= n) break;

        // ---- prefetch next iteration's F early (hides HBM latency) ----
        float nf[9];
        const bool havenext = (it + 1 < iters) && (ws + 64 < n);
        if (havenext) {
            long long sE = ws + 64 + l; if (sE > n - 1) sE = n - 1;
            const float* fp = Fs + sE * 9;
            #pragma unroll
            for (int q = 0; q < 9; ++q) nf[q] = fp[q];
        }

        float a = fr[0], b = fr[1], cc = fr[2];
        float d = fr[3], e = fr[4], f5 = fr[5];
        float g7 = fr[6], h7 = fr[7], i8 = fr[8];

        // ---- features (f32 compute, f16 store): F(9), cofactor(9), det ----
        float C00 = e * i8 - f5 * h7;
        float C01 = f5 * g7 - d * i8;
        float C02 = d * h7 - e * g7;
        float det = fmaf(a, C00, fmaf(b, C01, cc * C02));
        float C10 = cc * h7 - b * i8;
        float C11 = a * i8 - cc * g7;
        float C12 = b * g7 - a * h7;
        float C20 = b * f5 - cc * e;
        float C21 = cc * d - a * f5;
        float C22 = a * e - b * d;

        // ---- write this sample's 19 features (+pad) to per-wave LDS ----
        {
            uint2 v;
            v.x = pk2(a,   b);   v.y = pk2(cc,  d);   basep[l*5 + 0] = v;
            v.x = pk2(e,   f5);  v.y = pk2(g7,  h7);  basep[l*5 + 1] = v;
            v.x = pk2(i8,  C00); v.y = pk2(C01, C02); basep[l*5 + 2] = v;
            v.x = pk2(C10, C11); v.y = pk2(C12, C20); basep[l*5 + 3] = v;
            v.x = pk2(C21, C22); v.y = pk2(det, 0.0f); basep[l*5 + 4] = v;
        }
        asm volatile("s_waitcnt lgkmcnt(0)" ::: "memory");

        // ---- gather B-frags: tile m covers samples 16m+c ----
        uint2 rlo0 = basep[(16*0 + c)*5 + g];
        uint2 rlo1 = basep[(16*1 + c)*5 + g];
        uint2 rlo2 = basep[(16*2 + c)*5 + g];
        uint2 rlo3 = basep[(16*3 + c)*5 + g];
        uint2 rhi0 = basep[(16*0 + c)*5 + 4];   // same addr across g: broadcast
        uint2 rhi1 = basep[(16*1 + c)*5 + 4];
        uint2 rhi2 = basep[(16*2 + c)*5 + 4];
        uint2 rhi3 = basep[(16*3 + c)*5 + 4];

        // ---- Layer 1: K=32 via two chained MFMAs; output is t-domain ----
        f32x4 t10 = __builtin_amdgcn_mfma_f32_16x16x16f16(a1lo, h4(rlo0), cb1, 0, 0, 0);
        f32x4 t11 = __builtin_amdgcn_mfma_f32_16x16x16f16(a1lo, h4(rlo1), cb1, 0, 0, 0);
        f32x4 t12 = __builtin_amdgcn_mfma_f32_16x16x16f16(a1lo, h4(rlo2), cb1, 0, 0, 0);
        f32x4 t13 = __builtin_amdgcn_mfma_f32_16x16x16f16(a1lo, h4(rlo3), cb1, 0, 0, 0);
        t10 = __builtin_amdgcn_mfma_f32_16x16x16f16(a1hi, h4(rhi0), t10, 0, 0, 0);
        t11 = __builtin_amdgcn_mfma_f32_16x16x16f16(a1hi, h4(rhi1), t11, 0, 0, 0);
        t12 = __builtin_amdgcn_mfma_f32_16x16x16f16(a1hi, h4(rhi2), t12, 0, 0, 0);
        t13 = __builtin_amdgcn_mfma_f32_16x16x16f16(a1hi, h4(rhi3), t13, 0, 0, 0);

        // softplus (any sign) + pack: D-layout == next B-layout, in-register chain
        uint2 u0, u1, u2, u3;
        u0.x = pk2(sp_any(t10[0]), sp_any(t10[1])); u0.y = pk2(sp_any(t10[2]), sp_any(t10[3]));
        u1.x = pk2(sp_any(t11[0]), sp_any(t11[1])); u1.y = pk2(sp_any(t11[2]), sp_any(t11[3]));
        u2.x = pk2(sp_any(t12[0]), sp_any(t12[1])); u2.y = pk2(sp_any(t12[2]), sp_any(t12[3]));
        u3.x = pk2(sp_any(t13[0]), sp_any(t13[1])); u3.y = pk2(sp_any(t13[2]), sp_any(t13[3]));

        // ---- Layer 2 ----
        f32x4 d20 = __builtin_amdgcn_mfma_f32_16x16x16f16(a2, h4(u0), cb2, 0, 0, 0);
        f32x4 d21 = __builtin_amdgcn_mfma_f32_16x16x16f16(a2, h4(u1), cb2, 0, 0, 0);
        f32x4 d22 = __builtin_amdgcn_mfma_f32_16x16x16f16(a2, h4(u2), cb2, 0, 0, 0);
        f32x4 d23 = __builtin_amdgcn_mfma_f32_16x16x16f16(a2, h4(u3), cb2, 0, 0, 0);

        u0.x = pk2(sp_pos(d20[0]), sp_pos(d20[1])); u0.y = pk2(sp_pos(d20[2]), sp_pos(d20[3]));
        u1.x = pk2(sp_pos(d21[0]), sp_pos(d21[1])); u1.y = pk2(sp_pos(d21[2]), sp_pos(d21[3]));
        u2.x = pk2(sp_pos(d22[0]), sp_pos(d22[1])); u2.y = pk2(sp_pos(d22[2]), sp_pos(d22[3]));
        u3.x = pk2(sp_pos(d23[0]), sp_pos(d23[1])); u3.y = pk2(sp_pos(d23[2]), sp_pos(d23[3]));

        // ---- Layer 3 ----
        f32x4 d30 = __builtin_amdgcn_mfma_f32_16x16x16f16(a3, h4(u0), cb3, 0, 0, 0);
        f32x4 d31 = __builtin_amdgcn_mfma_f32_16x16x16f16(a3, h4(u1), cb3, 0, 0, 0);
        f32x4 d32 = __builtin_amdgcn_mfma_f32_16x16x16f16(a3, h4(u2), cb3, 0, 0, 0);
        f32x4 d33 = __builtin_amdgcn_mfma_f32_16x16x16f16(a3, h4(u3), cb3, 0, 0, 0);

        // ---- Layer 4: softplus then dot with W4*ln2; reduce over g-groups ----
        float y0 = sp_pos(d30[0])*w4v[0] + sp_pos(d30[1])*w4v[1] + sp_pos(d30[2])*w4v[2] + sp_pos(d30[3])*w4v[3];
        float y1 = sp_pos(d31[0])*w4v[0] + sp_pos(d31[1])*w4v[1] + sp_pos(d31[2])*w4v[2] + sp_pos(d31[3])*w4v[3];
        float y2 = sp_pos(d32[0])*w4v[0] + sp_pos(d32[1])*w4v[1] + sp_pos(d32[2])*w4v[2] + sp_pos(d32[3])*w4v[3];
        float y3 = sp_pos(d33[0])*w4v[0] + sp_pos(d33[1])*w4v[1] + sp_pos(d33[2])*w4v[2] + sp_pos(d33[3])*w4v[3];

        y0 += __shfl_xor(y0, 16, 64); y0 += __shfl_xor(y0, 32, 64);
        y1 += __shfl_xor(y1, 16, 64); y1 += __shfl_xor(y1, 32, 64);
        y2 += __shfl_xor(y2, 16, 64); y2 += __shfl_xor(y2, 32, 64);
        y3 += __shfl_xor(y3, 16, 64); y3 += __shfl_xor(y3, 32, 64);

        float yo = (g == 0) ? y0 : ((g == 1) ? y1 : ((g == 2) ? y2 : y3));
        yo += b4s;

        if (ws + l < n) out[ws + l] = yo;

        // rotate prefetched F into place
        if (havenext) {
            #pragma unroll
            for (int q = 0; q < 9; ++q) fr[q] = nf[q];
        }
    }
}

extern "C" void kernel_launch(void* const* d_in, const int* in_sizes, int n_in,
                              void* d_out, int out_size, void* d_ws, size_t ws_size,
                              hipStream_t stream) {
    const float* Fs = (const float*)d_in[0];
    const float* W1 = (const float*)d_in[1];
    const float* b1 = (const float*)d_in[2];
    const float* W2 = (const float*)d_in[3];
    const float* b2 = (const float*)d_in[4];
    const float* W3 = (const float*)d_in[5];
    const float* b3 = (const float*)d_in[6];
    const float* W4 = (const float*)d_in[7];
    const float* b4 = (const float*)d_in[8];
    float* out = (float*)d_out;

    int n = in_sizes[0] / 9;
    int waves = (n + 63) / 64;
    int iters = (waves + BLOCKS * 4 - 1) / (BLOCKS * 4);
    mlp_mfma_kernel<<<BLOCKS, TPB, 0, stream>>>(Fs, W1, b1, W2, b2, W3, b3, W4, b4,
                                                out, n, iters);
}